// Round 4
// baseline (1524.763 us; speedup 1.0000x reference)
//
#include <hip/hip_runtime.h>

// GCN 2-layer forward. Bucket-grouped edges (128 dst-nodes per bucket) +
// LDS-accumulator aggregation. No per-node sort, no fp32 global atomics.
// deg -> dinv ; chunksort(bucket-major ebuck) ;
// hs1=(x@W1)*dinv -> agg1(LDS acc, relu,+b1) -> hs2=(.@W2)*dinv -> agg2(+b2)

#define CHUNK 4096
#define BCAP  4096            // padded capacity per bucket (max observed ~2.3k)
#define NB_PAD 1024           // padded bucket-array size for LDS scan

__global__ __launch_bounds__(256) void deg_kernel(const int* __restrict__ dst,
                                                  int* __restrict__ deg, int nE) {
  int e = blockIdx.x * 256 + threadIdx.x;
  if (e < nE) atomicAdd(&deg[dst[e]], 1);
}

__global__ __launch_bounds__(256) void dinv_kernel(const int* __restrict__ deg,
                                                   float* __restrict__ dinv, int n) {
  int i = blockIdx.x * 256 + threadIdx.x;
  if (i < n) dinv[i] = rsqrtf((float)deg[i] + 1.0f);
}

__global__ __launch_bounds__(256) void initcur_kernel(int* __restrict__ bcursor,
                                                      int nb) {
  int i = blockIdx.x * 256 + threadIdx.x;
  if (i < nb) bcursor[i] = i * BCAP;
}

// Group edges by bucket b = dst>>7 into bucket-major ebuck (padded BCAP/bucket).
// Record = src | (dst&127)<<17.  Coalesced run-writes from an LDS-sorted copy.
__global__ __launch_bounds__(256) void chunksort_kernel(
    const int* __restrict__ src, const int* __restrict__ dst,
    int* __restrict__ bcursor, int* __restrict__ ebuck, int nE, int nb) {
  __shared__ int hist[NB_PAD];
  __shared__ int loff[NB_PAD];
  __shared__ int gbase[NB_PAD];
  __shared__ int lcur[NB_PAD];
  __shared__ int part[256];
  __shared__ int srec[CHUNK];
  __shared__ int saddr[CHUNK];
  const int t = threadIdx.x;
  const int e0 = blockIdx.x * CHUNK;
  const int n = min(CHUNK, nE - e0);
#pragma unroll
  for (int i = t; i < NB_PAD; i += 256) hist[i] = 0;
  __syncthreads();
  for (int i = t; i < n; i += 256) atomicAdd(&hist[dst[e0 + i] >> 7], 1);
  __syncthreads();
  // exclusive scan of hist[0..NB_PAD): 4 elems/thread + Hillis over 256 parts
  int h0 = hist[4 * t], h1 = hist[4 * t + 1], h2 = hist[4 * t + 2], h3 = hist[4 * t + 3];
  part[t] = h0 + h1 + h2 + h3;
  __syncthreads();
  for (int off = 1; off < 256; off <<= 1) {
    int v = (t >= off) ? part[t - off] : 0;
    __syncthreads();
    part[t] += v;
    __syncthreads();
  }
  int base = (t == 0) ? 0 : part[t - 1];
  loff[4 * t] = base;
  loff[4 * t + 1] = base + h0;
  loff[4 * t + 2] = base + h0 + h1;
  loff[4 * t + 3] = base + h0 + h1 + h2;
  __syncthreads();
  // reserve contiguous runs in global bucket regions
  for (int b = t; b < nb; b += 256) {
    int c = hist[b];
    gbase[b] = c ? atomicAdd(&bcursor[b], c) : 0;
    lcur[b] = loff[b];
  }
  __syncthreads();
  // LDS scatter: sorted record + its final global address
  for (int i = t; i < n; i += 256) {
    int d = dst[e0 + i];
    int b = d >> 7;
    int p = atomicAdd(&lcur[b], 1);
    srec[p] = src[e0 + i] | ((d & 127) << 17);
    saddr[p] = gbase[b] + (p - loff[b]);
  }
  __syncthreads();
  // run-contiguous global writes
  for (int i = t; i < n; i += 256) ebuck[saddr[i]] = srec[i];
}

// H[N,64] = (X[N,K] @ W[K,64]) * dinv[row].  4 rows x 4 ch per lane; W in LDS.
template <int K>
__global__ __launch_bounds__(256) void gemm64(const float* __restrict__ X,
                                              const float* __restrict__ W,
                                              const float* __restrict__ dinv,
                                              float* __restrict__ H, int N) {
  __shared__ float4 sW[K * 16];
  for (int i = threadIdx.x; i < K * 16; i += 256)
    sW[i] = reinterpret_cast<const float4*>(W)[i];
  __syncthreads();
  const int wave = threadIdx.x >> 6, lane = threadIdx.x & 63;
  const int rg = lane >> 4;
  const int cl = lane & 15;
  const int row0 = blockIdx.x * 64 + wave * 16 + rg * 4;
  if (row0 >= N) return;
  const float4* Xv = reinterpret_cast<const float4*>(X);
  const float4* xp[4];
#pragma unroll
  for (int r = 0; r < 4; ++r) {
    int row = min(row0 + r, N - 1);
    xp[r] = Xv + (size_t)row * (K / 4);
  }
  float acc[4][4] = {};
#pragma unroll 4
  for (int k4 = 0; k4 < K / 4; ++k4) {
    float4 xv[4];
#pragma unroll
    for (int r = 0; r < 4; ++r) xv[r] = xp[r][k4];
#pragma unroll
    for (int j = 0; j < 4; ++j) {
      float4 w = sW[(k4 * 4 + j) * 16 + cl];
#pragma unroll
      for (int r = 0; r < 4; ++r) {
        float xs = (&xv[r].x)[j];
        acc[r][0] += xs * w.x;
        acc[r][1] += xs * w.y;
        acc[r][2] += xs * w.z;
        acc[r][3] += xs * w.w;
      }
    }
  }
#pragma unroll
  for (int r = 0; r < 4; ++r) {
    int row = row0 + r;
    if (row < N) {
      float s = dinv[row];
      reinterpret_cast<float4*>(H)[(size_t)row * 16 + cl] =
          make_float4(acc[r][0] * s, acc[r][1] * s, acc[r][2] * s, acc[r][3] * s);
    }
  }
}

// One WG per 128-node bucket: LDS acc[128][64]; stream bucket's edge records,
// gather hs[src] (coalesced 256B/wave), ds_add into acc; fused epilogue.
template <bool RELU>
__global__ __launch_bounds__(256) void agg_lds(const float* __restrict__ hs,
                                               const int* __restrict__ ebuck,
                                               const int* __restrict__ bcursor,
                                               const float* __restrict__ dinv,
                                               const float* __restrict__ b,
                                               float* __restrict__ out, int N) {
  __shared__ float acc[128 * 64];  // 32KB
  const int t = threadIdx.x;
  const int bk = blockIdx.x;
  float4* accv = reinterpret_cast<float4*>(acc);
#pragma unroll
  for (int i = t; i < 128 * 16; i += 256) accv[i] = make_float4(0.f, 0.f, 0.f, 0.f);
  __syncthreads();
  const int base = bk * BCAP;
  const int cnt = bcursor[bk] - base;
  const int wv = t >> 6, lane = t & 63;
  const int* eb = ebuck + base;
  // 4 waves x 4-edge ILP
  for (int k = wv * 4; k < cnt; k += 16) {
    int rec[4];
    float v[4];
    int m = min(4, cnt - k);
#pragma unroll
    for (int u = 0; u < 4; ++u)
      if (u < m) rec[u] = eb[k + u];
#pragma unroll
    for (int u = 0; u < 4; ++u)
      if (u < m) v[u] = hs[(size_t)(rec[u] & 0x1FFFF) * 64 + lane];
#pragma unroll
    for (int u = 0; u < 4; ++u)
      if (u < m) {
        int ldst = (rec[u] >> 17) & 127;
        __hip_atomic_fetch_add(&acc[ldst * 64 + lane], v[u],
                               __ATOMIC_RELAXED, __HIP_MEMORY_SCOPE_WORKGROUP);
      }
  }
  __syncthreads();
  // epilogue: out[i] = act(dinv[i]*(acc + hs[i]) + bias)
  float bb = b[lane];
  for (int l = wv; l < 128; l += 4) {
    int node = bk * 128 + l;
    if (node >= N) break;
    float val = acc[l * 64 + lane] + hs[(size_t)node * 64 + lane];
    val = val * dinv[node] + bb;
    if (RELU) val = fmaxf(val, 0.f);
    out[(size_t)node * 64 + lane] = val;
  }
}

extern "C" void kernel_launch(void* const* d_in, const int* in_sizes, int n_in,
                              void* d_out, int out_size, void* d_ws, size_t ws_size,
                              hipStream_t stream) {
  const float* x  = (const float*)d_in[0];
  const int*   ei = (const int*)d_in[1];
  const float* W1 = (const float*)d_in[2];
  const float* b1 = (const float*)d_in[3];
  const float* W2 = (const float*)d_in[4];
  const float* b2 = (const float*)d_in[5];
  const int N = in_sizes[0] / 128;
  const int E = in_sizes[1] / 2;
  const int* src = ei;
  const int* dst = ei + E;
  const int nb = (N + 127) >> 7;  // 782 buckets

  char* ws = (char*)d_ws;
  int*   deg     = (int*)ws;                       // N ints
  float* dinv    = (float*)(ws + (1 << 19));       // N floats @ 512KB
  int*   bcursor = (int*)(ws + (1 << 20));         // nb ints  @ 1MB
  int*   ebuck   = (int*)(ws + (1 << 21));         // nb*BCAP ints @ 2MB (12.8MB)
  float* bufA    = (float*)(ws + (1 << 24));       // N*64 floats @ 16MB (25.6MB)
  float* out = (float*)d_out;

  // degree/dinv + bucket grouping (shared by both layers)
  hipMemsetAsync(deg, 0, N * sizeof(int), stream);
  deg_kernel<<<(E + 255) / 256, 256, 0, stream>>>(dst, deg, E);
  dinv_kernel<<<(N + 255) / 256, 256, 0, stream>>>(deg, dinv, N);
  initcur_kernel<<<(nb + 255) / 256, 256, 0, stream>>>(bcursor, nb);
  chunksort_kernel<<<(E + CHUNK - 1) / CHUNK, 256, 0, stream>>>(src, dst, bcursor,
                                                                ebuck, E, nb);

  // layer 1: hs1 -> bufA ; agg1 -> out (temp, becomes gemm2 input)
  gemm64<128><<<(N + 63) / 64, 256, 0, stream>>>(x, W1, dinv, bufA, N);
  agg_lds<true><<<nb, 256, 0, stream>>>(bufA, ebuck, bcursor, dinv, b1, out, N);
  // layer 2: hs2 -> bufA ; agg2 -> out (final)
  gemm64<64><<<(N + 63) / 64, 256, 0, stream>>>(out, W2, dinv, bufA, N);
  agg_lds<false><<<nb, 256, 0, stream>>>(bufA, ebuck, bcursor, dinv, b2, out, N);
}

// Round 5
// 224.868 us; speedup vs baseline: 6.7807x; 6.7807x over previous
//
#include <hip/hip_runtime.h>

// GCN 2-layer forward. Two-phase dst-sort to CSR (all writes coalesced),
// then one-wave-per-node gather aggregation at full occupancy.
// initcur -> chunksort (bucket-major ebuck) -> bscan -> bucketsort
//   (esrc fully dst-sorted, rowptr, dinv)  ->
// hs1=(x@W1)*dinv -> agg1(relu,self,+b1) -> hs2=(.@W2)*dinv -> agg2(+b2)

#define CHUNK 4096
#define BCAP  4096            // padded per-bucket capacity (max count ~2.3k)
#define NB_PAD 1024

__global__ __launch_bounds__(256) void initcur_kernel(int* __restrict__ bcursor,
                                                      int nb) {
  int i = blockIdx.x * 256 + threadIdx.x;
  if (i < nb) bcursor[i] = i * BCAP;
}

// Phase 1: group edges by bucket b = dst>>7 into bucket-major ebuck.
// Record = src | (dst&127)<<17.  Run-contiguous global writes from LDS sort.
__global__ __launch_bounds__(256) void chunksort_kernel(
    const int* __restrict__ src, const int* __restrict__ dst,
    int* __restrict__ bcursor, int* __restrict__ ebuck, int nE, int nb) {
  __shared__ int hist[NB_PAD];
  __shared__ int loff[NB_PAD];
  __shared__ int gbase[NB_PAD];
  __shared__ int lcur[NB_PAD];
  __shared__ int part[256];
  __shared__ int srec[CHUNK];
  __shared__ int saddr[CHUNK];
  const int t = threadIdx.x;
  const int e0 = blockIdx.x * CHUNK;
  const int n = min(CHUNK, nE - e0);
#pragma unroll
  for (int i = t; i < NB_PAD; i += 256) hist[i] = 0;
  __syncthreads();
  for (int i = t; i < n; i += 256) atomicAdd(&hist[dst[e0 + i] >> 7], 1);
  __syncthreads();
  int h0 = hist[4 * t], h1 = hist[4 * t + 1], h2 = hist[4 * t + 2], h3 = hist[4 * t + 3];
  part[t] = h0 + h1 + h2 + h3;
  __syncthreads();
  for (int off = 1; off < 256; off <<= 1) {
    int v = (t >= off) ? part[t - off] : 0;
    __syncthreads();
    part[t] += v;
    __syncthreads();
  }
  int base = (t == 0) ? 0 : part[t - 1];
  loff[4 * t] = base;
  loff[4 * t + 1] = base + h0;
  loff[4 * t + 2] = base + h0 + h1;
  loff[4 * t + 3] = base + h0 + h1 + h2;
  __syncthreads();
  for (int b = t; b < nb; b += 256) {
    int c = hist[b];
    gbase[b] = c ? atomicAdd(&bcursor[b], c) : 0;
    lcur[b] = loff[b];
  }
  __syncthreads();
  for (int i = t; i < n; i += 256) {
    int d = dst[e0 + i];
    int b = d >> 7;
    int p = atomicAdd(&lcur[b], 1);
    srec[p] = src[e0 + i] | ((d & 127) << 17);
    saddr[p] = gbase[b] + (p - loff[b]);
  }
  __syncthreads();
  for (int i = t; i < n; i += 256) ebuck[saddr[i]] = srec[i];
}

// Exclusive scan over 782 bucket counts (single WG).
__global__ __launch_bounds__(1024) void bscan_kernel(const int* __restrict__ bcursor,
                                                     int* __restrict__ bbase, int nb) {
  __shared__ int part[1024];
  const int t = threadIdx.x;
  int c = (t < nb) ? (bcursor[t] - t * BCAP) : 0;
  part[t] = c;
  __syncthreads();
  for (int off = 1; off < 1024; off <<= 1) {
    int v = (t >= off) ? part[t - off] : 0;
    __syncthreads();
    part[t] += v;
    __syncthreads();
  }
  if (t < nb) bbase[t] = part[t] - c;  // exclusive
}

// Phase 2: per-bucket counting sort (128 local-dst keys) -> fully sorted esrc
// (coalesced write), plus rowptr and dinv straight from the histogram.
__global__ __launch_bounds__(256) void bucketsort_kernel(
    const int* __restrict__ ebuck, const int* __restrict__ bcursor,
    const int* __restrict__ bbase, int* __restrict__ esrc,
    int* __restrict__ rowptr, float* __restrict__ dinv, int N, int E, int nb) {
  __shared__ int hist[128];
  __shared__ int sc[128];
  __shared__ int rowcur[128];
  __shared__ int ssrc[BCAP];
  const int t = threadIdx.x;
  const int bk = blockIdx.x;
  const int base = bk * BCAP;
  const int cnt = bcursor[bk] - base;
  const int gb = bbase[bk];
  if (t < 128) hist[t] = 0;
  __syncthreads();
  for (int i = t; i < cnt; i += 256)
    atomicAdd(&hist[(ebuck[base + i] >> 17) & 127], 1);
  __syncthreads();
  if (t < 128) sc[t] = hist[t];
  __syncthreads();
  for (int off = 1; off < 128; off <<= 1) {
    int v = 0;
    if (t < 128 && t >= off) v = sc[t - off];
    __syncthreads();
    if (t < 128) sc[t] += v;
    __syncthreads();
  }
  if (t < 128) {
    int excl = (t == 0) ? 0 : sc[t - 1];
    rowcur[t] = excl;
    int node = bk * 128 + t;
    if (node < N) {
      rowptr[node] = gb + excl;
      dinv[node] = rsqrtf((float)hist[t] + 1.0f);
    }
  }
  if (bk == nb - 1 && t == 0) rowptr[N] = E;
  __syncthreads();
  for (int i = t; i < cnt; i += 256) {
    int rec = ebuck[base + i];
    int p = atomicAdd(&rowcur[(rec >> 17) & 127], 1);
    ssrc[p] = rec & 0x1FFFF;
  }
  __syncthreads();
  for (int i = t; i < cnt; i += 256) esrc[gb + i] = ssrc[i];
}

// H[N,64] = (X[N,K] @ W[K,64]) * dinv[row].  4 rows x 4 ch per lane; W in LDS.
template <int K>
__global__ __launch_bounds__(256) void gemm64(const float* __restrict__ X,
                                              const float* __restrict__ W,
                                              const float* __restrict__ dinv,
                                              float* __restrict__ H, int N) {
  __shared__ float4 sW[K * 16];
  for (int i = threadIdx.x; i < K * 16; i += 256)
    sW[i] = reinterpret_cast<const float4*>(W)[i];
  __syncthreads();
  const int wave = threadIdx.x >> 6, lane = threadIdx.x & 63;
  const int rg = lane >> 4;
  const int cl = lane & 15;
  const int row0 = blockIdx.x * 64 + wave * 16 + rg * 4;
  if (row0 >= N) return;
  const float4* Xv = reinterpret_cast<const float4*>(X);
  const float4* xp[4];
#pragma unroll
  for (int r = 0; r < 4; ++r) {
    int row = min(row0 + r, N - 1);
    xp[r] = Xv + (size_t)row * (K / 4);
  }
  float acc[4][4] = {};
#pragma unroll 4
  for (int k4 = 0; k4 < K / 4; ++k4) {
    float4 xv[4];
#pragma unroll
    for (int r = 0; r < 4; ++r) xv[r] = xp[r][k4];
#pragma unroll
    for (int j = 0; j < 4; ++j) {
      float4 w = sW[(k4 * 4 + j) * 16 + cl];
#pragma unroll
      for (int r = 0; r < 4; ++r) {
        float xs = (&xv[r].x)[j];
        acc[r][0] += xs * w.x;
        acc[r][1] += xs * w.y;
        acc[r][2] += xs * w.z;
        acc[r][3] += xs * w.w;
      }
    }
  }
#pragma unroll
  for (int r = 0; r < 4; ++r) {
    int row = row0 + r;
    if (row < N) {
      float s = dinv[row];
      reinterpret_cast<float4*>(H)[(size_t)row * 16 + cl] =
          make_float4(acc[r][0] * s, acc[r][1] * s, acc[r][2] * s, acc[r][3] * s);
    }
  }
}

// One wave per node: out[i] = act(dinv[i]*(sum_edges hs[esrc] + hs[i]) + b)
// 4 edge-groups x 16 lanes x float4, manual 2x unroll (8 gather-lines in flight).
template <bool RELU>
__global__ __launch_bounds__(256) void agg_kernel(const float* __restrict__ hs,
                                                  const int* __restrict__ rowptr,
                                                  const int* __restrict__ esrc,
                                                  const float* __restrict__ dinv,
                                                  const float* __restrict__ b,
                                                  float* __restrict__ out, int N) {
  const int node = blockIdx.x * 4 + (threadIdx.x >> 6);
  if (node >= N) return;
  const int lane = threadIdx.x & 63;
  const int g = lane >> 4, cl = lane & 15;
  const float4* hv = reinterpret_cast<const float4*>(hs);
  const int beg = rowptr[node], end = rowptr[node + 1];
  float4 a0 = make_float4(0.f, 0.f, 0.f, 0.f);
  float4 a1 = make_float4(0.f, 0.f, 0.f, 0.f);
  int k = beg + g;
  for (; k + 4 < end; k += 8) {
    int s0 = esrc[k], s1 = esrc[k + 4];
    float4 v0 = hv[(size_t)s0 * 16 + cl];
    float4 v1 = hv[(size_t)s1 * 16 + cl];
    a0.x += v0.x; a0.y += v0.y; a0.z += v0.z; a0.w += v0.w;
    a1.x += v1.x; a1.y += v1.y; a1.z += v1.z; a1.w += v1.w;
  }
  if (k < end) {
    float4 v = hv[(size_t)esrc[k] * 16 + cl];
    a0.x += v.x; a0.y += v.y; a0.z += v.z; a0.w += v.w;
  }
  a0.x += a1.x; a0.y += a1.y; a0.z += a1.z; a0.w += a1.w;
#pragma unroll
  for (int off = 16; off <= 32; off <<= 1) {
    a0.x += __shfl_xor(a0.x, off);
    a0.y += __shfl_xor(a0.y, off);
    a0.z += __shfl_xor(a0.z, off);
    a0.w += __shfl_xor(a0.w, off);
  }
  if (g == 0) {
    float4 self = hv[(size_t)node * 16 + cl];
    float di = dinv[node];
    float4 bb = reinterpret_cast<const float4*>(b)[cl];
    float4 r;
    r.x = (a0.x + self.x) * di + bb.x;
    r.y = (a0.y + self.y) * di + bb.y;
    r.z = (a0.z + self.z) * di + bb.z;
    r.w = (a0.w + self.w) * di + bb.w;
    if (RELU) {
      r.x = fmaxf(r.x, 0.f); r.y = fmaxf(r.y, 0.f);
      r.z = fmaxf(r.z, 0.f); r.w = fmaxf(r.w, 0.f);
    }
    reinterpret_cast<float4*>(out)[(size_t)node * 16 + cl] = r;
  }
}

extern "C" void kernel_launch(void* const* d_in, const int* in_sizes, int n_in,
                              void* d_out, int out_size, void* d_ws, size_t ws_size,
                              hipStream_t stream) {
  const float* x  = (const float*)d_in[0];
  const int*   ei = (const int*)d_in[1];
  const float* W1 = (const float*)d_in[2];
  const float* b1 = (const float*)d_in[3];
  const float* W2 = (const float*)d_in[4];
  const float* b2 = (const float*)d_in[5];
  const int N = in_sizes[0] / 128;
  const int E = in_sizes[1] / 2;
  const int* src = ei;
  const int* dst = ei + E;
  const int nb = (N + 127) >> 7;  // 782 buckets

  char* ws = (char*)d_ws;
  int*   bcursor = (int*)ws;                       // nb ints
  int*   bbase   = (int*)(ws + (1 << 19));         // nb ints   @ 512KB
  float* dinv    = (float*)(ws + (1 << 20));       // N floats  @ 1MB
  int*   rowptr  = (int*)(ws + 3 * (1 << 19));     // N+1 ints  @ 1.5MB
  int*   esrc    = (int*)(ws + (1 << 21));         // E ints    @ 2MB   (6.4MB)
  int*   ebuck   = (int*)(ws + 9 * (1 << 20));     // nb*BCAP   @ 9MB   (12.8MB)
  float* bufA    = (float*)(ws + 22 * (1 << 20));  // N*64      @ 22MB  (25.6MB)
  float* out = (float*)d_out;

  // CSR build (shared by both layers); all global writes run-coalesced
  initcur_kernel<<<(nb + 255) / 256, 256, 0, stream>>>(bcursor, nb);
  chunksort_kernel<<<(E + CHUNK - 1) / CHUNK, 256, 0, stream>>>(src, dst, bcursor,
                                                                ebuck, E, nb);
  bscan_kernel<<<1, 1024, 0, stream>>>(bcursor, bbase, nb);
  bucketsort_kernel<<<nb, 256, 0, stream>>>(ebuck, bcursor, bbase, esrc, rowptr,
                                            dinv, N, E, nb);

  const int aggGrid = (N + 3) / 4;
  // layer 1: hs1 -> bufA ; agg1 -> out (temp, becomes gemm2 input)
  gemm64<128><<<(N + 63) / 64, 256, 0, stream>>>(x, W1, dinv, bufA, N);
  agg_kernel<true><<<aggGrid, 256, 0, stream>>>(bufA, rowptr, esrc, dinv, b1, out, N);
  // layer 2: hs2 -> bufA ; agg2 -> out (final)
  gemm64<64><<<(N + 63) / 64, 256, 0, stream>>>(out, W2, dinv, bufA, N);
  agg_kernel<false><<<aggGrid, 256, 0, stream>>>(bufA, rowptr, esrc, dinv, b2, out, N);
}

// Round 6
// 196.634 us; speedup vs baseline: 7.7543x; 1.1436x over previous
//
#include <hip/hip_runtime.h>
#include <hip/hip_fp16.h>

// GCN 2-layer forward. Two-phase dst-sort to CSR (all writes coalesced),
// one-wave-per-node gather aggregation. Message table hs stored in FP16
// (halves the per-XCD compulsory L2-miss gather traffic); all accumulation fp32.

#define CHUNK 4096
#define BCAP  4096            // padded per-bucket capacity (max count ~2.3k)
#define NB_PAD 1024

__global__ __launch_bounds__(256) void initcur_kernel(int* __restrict__ bcursor,
                                                      int nb) {
  int i = blockIdx.x * 256 + threadIdx.x;
  if (i < nb) bcursor[i] = i * BCAP;
}

// Phase 1: group edges by bucket b = dst>>7 into bucket-major ebuck.
// Record = src | (dst&127)<<17.  Run-contiguous global writes from LDS sort.
__global__ __launch_bounds__(256) void chunksort_kernel(
    const int* __restrict__ src, const int* __restrict__ dst,
    int* __restrict__ bcursor, int* __restrict__ ebuck, int nE, int nb) {
  __shared__ int hist[NB_PAD];
  __shared__ int loff[NB_PAD];
  __shared__ int gbase[NB_PAD];
  __shared__ int lcur[NB_PAD];
  __shared__ int part[256];
  __shared__ int srec[CHUNK];
  __shared__ int saddr[CHUNK];
  const int t = threadIdx.x;
  const int e0 = blockIdx.x * CHUNK;
  const int n = min(CHUNK, nE - e0);
#pragma unroll
  for (int i = t; i < NB_PAD; i += 256) hist[i] = 0;
  __syncthreads();
  for (int i = t; i < n; i += 256) atomicAdd(&hist[dst[e0 + i] >> 7], 1);
  __syncthreads();
  int h0 = hist[4 * t], h1 = hist[4 * t + 1], h2 = hist[4 * t + 2], h3 = hist[4 * t + 3];
  part[t] = h0 + h1 + h2 + h3;
  __syncthreads();
  for (int off = 1; off < 256; off <<= 1) {
    int v = (t >= off) ? part[t - off] : 0;
    __syncthreads();
    part[t] += v;
    __syncthreads();
  }
  int base = (t == 0) ? 0 : part[t - 1];
  loff[4 * t] = base;
  loff[4 * t + 1] = base + h0;
  loff[4 * t + 2] = base + h0 + h1;
  loff[4 * t + 3] = base + h0 + h1 + h2;
  __syncthreads();
  for (int b = t; b < nb; b += 256) {
    int c = hist[b];
    gbase[b] = c ? atomicAdd(&bcursor[b], c) : 0;
    lcur[b] = loff[b];
  }
  __syncthreads();
  for (int i = t; i < n; i += 256) {
    int d = dst[e0 + i];
    int b = d >> 7;
    int p = atomicAdd(&lcur[b], 1);
    srec[p] = src[e0 + i] | ((d & 127) << 17);
    saddr[p] = gbase[b] + (p - loff[b]);
  }
  __syncthreads();
  for (int i = t; i < n; i += 256) ebuck[saddr[i]] = srec[i];
}

// Exclusive scan over 782 bucket counts (single WG).
__global__ __launch_bounds__(1024) void bscan_kernel(const int* __restrict__ bcursor,
                                                     int* __restrict__ bbase, int nb) {
  __shared__ int part[1024];
  const int t = threadIdx.x;
  int c = (t < nb) ? (bcursor[t] - t * BCAP) : 0;
  part[t] = c;
  __syncthreads();
  for (int off = 1; off < 1024; off <<= 1) {
    int v = (t >= off) ? part[t - off] : 0;
    __syncthreads();
    part[t] += v;
    __syncthreads();
  }
  if (t < nb) bbase[t] = part[t] - c;  // exclusive
}

// Phase 2: per-bucket counting sort (128 local-dst keys) -> fully sorted esrc
// (coalesced write), plus rowptr and dinv straight from the histogram.
__global__ __launch_bounds__(256) void bucketsort_kernel(
    const int* __restrict__ ebuck, const int* __restrict__ bcursor,
    const int* __restrict__ bbase, int* __restrict__ esrc,
    int* __restrict__ rowptr, float* __restrict__ dinv, int N, int E, int nb) {
  __shared__ int hist[128];
  __shared__ int sc[128];
  __shared__ int rowcur[128];
  __shared__ int ssrc[BCAP];
  const int t = threadIdx.x;
  const int bk = blockIdx.x;
  const int base = bk * BCAP;
  const int cnt = bcursor[bk] - base;
  const int gb = bbase[bk];
  if (t < 128) hist[t] = 0;
  __syncthreads();
  for (int i = t; i < cnt; i += 256)
    atomicAdd(&hist[(ebuck[base + i] >> 17) & 127], 1);
  __syncthreads();
  if (t < 128) sc[t] = hist[t];
  __syncthreads();
  for (int off = 1; off < 128; off <<= 1) {
    int v = 0;
    if (t < 128 && t >= off) v = sc[t - off];
    __syncthreads();
    if (t < 128) sc[t] += v;
    __syncthreads();
  }
  if (t < 128) {
    int excl = (t == 0) ? 0 : sc[t - 1];
    rowcur[t] = excl;
    int node = bk * 128 + t;
    if (node < N) {
      rowptr[node] = gb + excl;
      dinv[node] = rsqrtf((float)hist[t] + 1.0f);
    }
  }
  if (bk == nb - 1 && t == 0) rowptr[N] = E;
  __syncthreads();
  for (int i = t; i < cnt; i += 256) {
    int rec = ebuck[base + i];
    int p = atomicAdd(&rowcur[(rec >> 17) & 127], 1);
    ssrc[p] = rec & 0x1FFFF;
  }
  __syncthreads();
  for (int i = t; i < cnt; i += 256) esrc[gb + i] = ssrc[i];
}

// H[N,64](fp16) = (X[N,K](fp32) @ W[K,64]) * dinv[row]. 4 rows x 4 ch per lane.
template <int K>
__global__ __launch_bounds__(256) void gemm64(const float* __restrict__ X,
                                              const float* __restrict__ W,
                                              const float* __restrict__ dinv,
                                              __half* __restrict__ H, int N) {
  __shared__ float4 sW[K * 16];
  for (int i = threadIdx.x; i < K * 16; i += 256)
    sW[i] = reinterpret_cast<const float4*>(W)[i];
  __syncthreads();
  const int wave = threadIdx.x >> 6, lane = threadIdx.x & 63;
  const int rg = lane >> 4;
  const int cl = lane & 15;
  const int row0 = blockIdx.x * 64 + wave * 16 + rg * 4;
  if (row0 >= N) return;
  const float4* Xv = reinterpret_cast<const float4*>(X);
  const float4* xp[4];
#pragma unroll
  for (int r = 0; r < 4; ++r) {
    int row = min(row0 + r, N - 1);
    xp[r] = Xv + (size_t)row * (K / 4);
  }
  float acc[4][4] = {};
#pragma unroll 4
  for (int k4 = 0; k4 < K / 4; ++k4) {
    float4 xv[4];
#pragma unroll
    for (int r = 0; r < 4; ++r) xv[r] = xp[r][k4];
#pragma unroll
    for (int j = 0; j < 4; ++j) {
      float4 w = sW[(k4 * 4 + j) * 16 + cl];
#pragma unroll
      for (int r = 0; r < 4; ++r) {
        float xs = (&xv[r].x)[j];
        acc[r][0] += xs * w.x;
        acc[r][1] += xs * w.y;
        acc[r][2] += xs * w.z;
        acc[r][3] += xs * w.w;
      }
    }
  }
#pragma unroll
  for (int r = 0; r < 4; ++r) {
    int row = row0 + r;
    if (row < N) {
      float s = dinv[row];
      __half2 h01 = __floats2half2_rn(acc[r][0] * s, acc[r][1] * s);
      __half2 h23 = __floats2half2_rn(acc[r][2] * s, acc[r][3] * s);
      uint2 pack;
      pack.x = *reinterpret_cast<unsigned int*>(&h01);
      pack.y = *reinterpret_cast<unsigned int*>(&h23);
      reinterpret_cast<uint2*>(H)[(size_t)row * 16 + cl] = pack;
    }
  }
}

// One wave per node: out[i] = act(dinv[i]*(sum_edges hs[esrc] + hs[i]) + b)
// hs is fp16 (row = 128B); 4 edge-groups x 16 lanes x 8B, 2x unroll.
template <bool RELU>
__global__ __launch_bounds__(256) void agg_kernel(const __half* __restrict__ hs,
                                                  const int* __restrict__ rowptr,
                                                  const int* __restrict__ esrc,
                                                  const float* __restrict__ dinv,
                                                  const float* __restrict__ b,
                                                  float* __restrict__ out, int N) {
  const int node = blockIdx.x * 4 + (threadIdx.x >> 6);
  if (node >= N) return;
  const int lane = threadIdx.x & 63;
  const int g = lane >> 4, cl = lane & 15;
  const uint2* hv = reinterpret_cast<const uint2*>(hs);
  const int beg = rowptr[node], end = rowptr[node + 1];
  float4 a0 = make_float4(0.f, 0.f, 0.f, 0.f);
  float4 a1 = make_float4(0.f, 0.f, 0.f, 0.f);
  int k = beg + g;
  for (; k + 4 < end; k += 8) {
    int s0 = esrc[k], s1 = esrc[k + 4];
    uint2 v0 = hv[(size_t)s0 * 16 + cl];
    uint2 v1 = hv[(size_t)s1 * 16 + cl];
    float2 f00 = __half22float2(*reinterpret_cast<__half2*>(&v0.x));
    float2 f01 = __half22float2(*reinterpret_cast<__half2*>(&v0.y));
    float2 f10 = __half22float2(*reinterpret_cast<__half2*>(&v1.x));
    float2 f11 = __half22float2(*reinterpret_cast<__half2*>(&v1.y));
    a0.x += f00.x; a0.y += f00.y; a0.z += f01.x; a0.w += f01.y;
    a1.x += f10.x; a1.y += f10.y; a1.z += f11.x; a1.w += f11.y;
  }
  if (k < end) {
    uint2 v0 = hv[(size_t)esrc[k] * 16 + cl];
    float2 f00 = __half22float2(*reinterpret_cast<__half2*>(&v0.x));
    float2 f01 = __half22float2(*reinterpret_cast<__half2*>(&v0.y));
    a0.x += f00.x; a0.y += f00.y; a0.z += f01.x; a0.w += f01.y;
  }
  a0.x += a1.x; a0.y += a1.y; a0.z += a1.z; a0.w += a1.w;
#pragma unroll
  for (int off = 16; off <= 32; off <<= 1) {
    a0.x += __shfl_xor(a0.x, off);
    a0.y += __shfl_xor(a0.y, off);
    a0.z += __shfl_xor(a0.z, off);
    a0.w += __shfl_xor(a0.w, off);
  }
  if (g == 0) {
    uint2 sv = hv[(size_t)node * 16 + cl];
    float2 s01 = __half22float2(*reinterpret_cast<__half2*>(&sv.x));
    float2 s23 = __half22float2(*reinterpret_cast<__half2*>(&sv.y));
    float di = dinv[node];
    float4 bb = reinterpret_cast<const float4*>(b)[cl];
    float4 r;
    r.x = (a0.x + s01.x) * di + bb.x;
    r.y = (a0.y + s01.y) * di + bb.y;
    r.z = (a0.z + s23.x) * di + bb.z;
    r.w = (a0.w + s23.y) * di + bb.w;
    if (RELU) {
      r.x = fmaxf(r.x, 0.f); r.y = fmaxf(r.y, 0.f);
      r.z = fmaxf(r.z, 0.f); r.w = fmaxf(r.w, 0.f);
    }
    reinterpret_cast<float4*>(out)[(size_t)node * 16 + cl] = r;
  }
}

extern "C" void kernel_launch(void* const* d_in, const int* in_sizes, int n_in,
                              void* d_out, int out_size, void* d_ws, size_t ws_size,
                              hipStream_t stream) {
  const float* x  = (const float*)d_in[0];
  const int*   ei = (const int*)d_in[1];
  const float* W1 = (const float*)d_in[2];
  const float* b1 = (const float*)d_in[3];
  const float* W2 = (const float*)d_in[4];
  const float* b2 = (const float*)d_in[5];
  const int N = in_sizes[0] / 128;
  const int E = in_sizes[1] / 2;
  const int* src = ei;
  const int* dst = ei + E;
  const int nb = (N + 127) >> 7;  // 782 buckets

  char* ws = (char*)d_ws;
  int*    bcursor = (int*)ws;                       // nb ints
  int*    bbase   = (int*)(ws + (1 << 19));         // nb ints   @ 512KB
  float*  dinv    = (float*)(ws + (1 << 20));       // N floats  @ 1MB
  int*    rowptr  = (int*)(ws + 3 * (1 << 19));     // N+1 ints  @ 1.5MB
  int*    esrc    = (int*)(ws + (1 << 21));         // E ints    @ 2MB   (6.4MB)
  int*    ebuck   = (int*)(ws + 9 * (1 << 20));     // nb*BCAP   @ 9MB   (12.8MB)
  __half* bufH    = (__half*)(ws + 22 * (1 << 20)); // N*64 fp16 @ 22MB  (12.8MB)
  float*  bufY    = (float*)(ws + 36 * (1 << 20));  // N*64 fp32 @ 36MB  (25.6MB)
  float*  out = (float*)d_out;

  // CSR build (shared by both layers); all global writes run-coalesced
  initcur_kernel<<<(nb + 255) / 256, 256, 0, stream>>>(bcursor, nb);
  chunksort_kernel<<<(E + CHUNK - 1) / CHUNK, 256, 0, stream>>>(src, dst, bcursor,
                                                                ebuck, E, nb);
  bscan_kernel<<<1, 1024, 0, stream>>>(bcursor, bbase, nb);
  bucketsort_kernel<<<nb, 256, 0, stream>>>(ebuck, bcursor, bbase, esrc, rowptr,
                                            dinv, N, E, nb);

  const int aggGrid = (N + 3) / 4;
  // layer 1: hs1(fp16) -> bufH ; y1(fp32) -> bufY
  gemm64<128><<<(N + 63) / 64, 256, 0, stream>>>(x, W1, dinv, bufH, N);
  agg_kernel<true><<<aggGrid, 256, 0, stream>>>(bufH, rowptr, esrc, dinv, b1, bufY, N);
  // layer 2: hs2(fp16) -> bufH ; y2 -> out
  gemm64<64><<<(N + 63) / 64, 256, 0, stream>>>(bufY, W2, dinv, bufH, N);
  agg_kernel<false><<<aggGrid, 256, 0, stream>>>(bufH, rowptr, esrc, dinv, b2, out, N);
}

// Round 7
// 174.039 us; speedup vs baseline: 8.7610x; 1.1298x over previous
//
#include <hip/hip_runtime.h>
#include <hip/hip_fp16.h>

// GCN 2-layer forward. CSR via two-phase dst-sort (coalesced writes),
// MFMA fp16 GEMMs (fp32 accum), fp16 message tables, gather aggregation.

#define CHUNK 4096
#define BCAP  4096
#define NB_PAD 1024

typedef _Float16 f16x8 __attribute__((ext_vector_type(8)));
typedef float f32x4 __attribute__((ext_vector_type(4)));

__device__ __forceinline__ unsigned int pack2(float a, float b) {
  __half2 h = __floats2half2_rn(a, b);
  return *reinterpret_cast<unsigned int*>(&h);
}

__global__ __launch_bounds__(256) void initcur_kernel(int* __restrict__ bcursor,
                                                      int nb) {
  int i = blockIdx.x * 256 + threadIdx.x;
  if (i < nb) bcursor[i] = i * BCAP;
}

// Phase 1: group edges by bucket b = dst>>7 into bucket-major ebuck.
__global__ __launch_bounds__(256) void chunksort_kernel(
    const int* __restrict__ src, const int* __restrict__ dst,
    int* __restrict__ bcursor, int* __restrict__ ebuck, int nE, int nb) {
  __shared__ int hist[NB_PAD];
  __shared__ int loff[NB_PAD];
  __shared__ int gbase[NB_PAD];
  __shared__ int lcur[NB_PAD];
  __shared__ int part[256];
  __shared__ int srec[CHUNK];
  __shared__ int saddr[CHUNK];
  const int t = threadIdx.x;
  const int e0 = blockIdx.x * CHUNK;
  const int n = min(CHUNK, nE - e0);
#pragma unroll
  for (int i = t; i < NB_PAD; i += 256) hist[i] = 0;
  __syncthreads();
  for (int i = t; i < n; i += 256) atomicAdd(&hist[dst[e0 + i] >> 7], 1);
  __syncthreads();
  int h0 = hist[4 * t], h1 = hist[4 * t + 1], h2 = hist[4 * t + 2], h3 = hist[4 * t + 3];
  part[t] = h0 + h1 + h2 + h3;
  __syncthreads();
  for (int off = 1; off < 256; off <<= 1) {
    int v = (t >= off) ? part[t - off] : 0;
    __syncthreads();
    part[t] += v;
    __syncthreads();
  }
  int base = (t == 0) ? 0 : part[t - 1];
  loff[4 * t] = base;
  loff[4 * t + 1] = base + h0;
  loff[4 * t + 2] = base + h0 + h1;
  loff[4 * t + 3] = base + h0 + h1 + h2;
  __syncthreads();
  for (int b = t; b < nb; b += 256) {
    int c = hist[b];
    gbase[b] = c ? atomicAdd(&bcursor[b], c) : 0;
    lcur[b] = loff[b];
  }
  __syncthreads();
  for (int i = t; i < n; i += 256) {
    int d = dst[e0 + i];
    int b = d >> 7;
    int p = atomicAdd(&lcur[b], 1);
    srec[p] = src[e0 + i] | ((d & 127) << 17);
    saddr[p] = gbase[b] + (p - loff[b]);
  }
  __syncthreads();
  for (int i = t; i < n; i += 256) ebuck[saddr[i]] = srec[i];
}

__global__ __launch_bounds__(1024) void bscan_kernel(const int* __restrict__ bcursor,
                                                     int* __restrict__ bbase, int nb) {
  __shared__ int part[1024];
  const int t = threadIdx.x;
  int c = (t < nb) ? (bcursor[t] - t * BCAP) : 0;
  part[t] = c;
  __syncthreads();
  for (int off = 1; off < 1024; off <<= 1) {
    int v = (t >= off) ? part[t - off] : 0;
    __syncthreads();
    part[t] += v;
    __syncthreads();
  }
  if (t < nb) bbase[t] = part[t] - c;  // exclusive
}

// Phase 2: per-bucket counting sort -> fully dst-sorted esrc + rowptr + dinv.
__global__ __launch_bounds__(256) void bucketsort_kernel(
    const int* __restrict__ ebuck, const int* __restrict__ bcursor,
    const int* __restrict__ bbase, int* __restrict__ esrc,
    int* __restrict__ rowptr, float* __restrict__ dinv, int N, int E, int nb) {
  __shared__ int hist[128];
  __shared__ int sc[128];
  __shared__ int rowcur[128];
  __shared__ int ssrc[BCAP];
  const int t = threadIdx.x;
  const int bk = blockIdx.x;
  const int base = bk * BCAP;
  const int cnt = bcursor[bk] - base;
  const int gb = bbase[bk];
  if (t < 128) hist[t] = 0;
  __syncthreads();
  for (int i = t; i < cnt; i += 256)
    atomicAdd(&hist[(ebuck[base + i] >> 17) & 127], 1);
  __syncthreads();
  if (t < 128) sc[t] = hist[t];
  __syncthreads();
  for (int off = 1; off < 128; off <<= 1) {
    int v = 0;
    if (t < 128 && t >= off) v = sc[t - off];
    __syncthreads();
    if (t < 128) sc[t] += v;
    __syncthreads();
  }
  if (t < 128) {
    int excl = (t == 0) ? 0 : sc[t - 1];
    rowcur[t] = excl;
    int node = bk * 128 + t;
    if (node < N) {
      rowptr[node] = gb + excl;
      dinv[node] = rsqrtf((float)hist[t] + 1.0f);
    }
  }
  if (bk == nb - 1 && t == 0) rowptr[N] = E;
  __syncthreads();
  for (int i = t; i < cnt; i += 256) {
    int rec = ebuck[base + i];
    int p = atomicAdd(&rowcur[(rec >> 17) & 127], 1);
    ssrc[p] = rec & 0x1FFFF;
  }
  __syncthreads();
  for (int i = t; i < cnt; i += 256) esrc[gb + i] = ssrc[i];
}

// H[N,64](fp16) = (X[N,K] @ W[K,64]) * dinv[row], via mfma_f32_16x16x32_f16.
// Block: 256 thr = 4 waves, 128 rows. LDS: A fp16 [128][K] + B^T fp16 [64][K],
// both XOR-swizzled (byte ^= (row&7)<<4) on write AND read (16-way fix).
template <int K, bool IN_HALF>
__global__ __launch_bounds__(256) void gemm_mfma(const void* __restrict__ Xin,
                                                 const float* __restrict__ W,
                                                 const float* __restrict__ dinv,
                                                 __half* __restrict__ H, int N) {
  __shared__ __align__(16) unsigned char sA[128 * K * 2];
  __shared__ __align__(16) unsigned char sB[64 * K * 2];
  const int t = threadIdx.x;
  const int brow = blockIdx.x * 128;
  // stage A: 128 rows x K halves, 16B chunks, coalesced global reads
  constexpr int CH = K / 8;
  for (int idx = t; idx < 128 * CH; idx += 256) {
    int r = idx / CH, c = idx - r * CH;
    int row = brow + r;
    if (row >= N) row = N - 1;
    unsigned int off = (unsigned int)((r * K + c * 8) * 2) ^ ((r & 7) << 4);
    uint4 pk;
    if constexpr (IN_HALF) {
      pk = *reinterpret_cast<const uint4*>((const __half*)Xin + (size_t)row * K + c * 8);
    } else {
      const float4* xp =
          reinterpret_cast<const float4*>((const float*)Xin + (size_t)row * K + c * 8);
      float4 f0 = xp[0], f1 = xp[1];
      pk.x = pack2(f0.x, f0.y);
      pk.y = pack2(f0.z, f0.w);
      pk.z = pack2(f1.x, f1.y);
      pk.w = pack2(f1.z, f1.w);
    }
    *reinterpret_cast<uint4*>(sA + off) = pk;
  }
  // stage B^T: Wt[n][k] fp16, swizzled
  for (int idx = t; idx < K * 64; idx += 256) {
    int k = idx >> 6, n = idx & 63;
    __half h = __float2half_rn(W[idx]);
    unsigned int off = (unsigned int)((n * K + k) * 2) ^ ((n & 7) << 4);
    *reinterpret_cast<unsigned short*>(sB + off) =
        *reinterpret_cast<unsigned short*>(&h);
  }
  __syncthreads();

  const int wv = t >> 6, l = t & 63;
  const int lr = l & 15;          // A row / B col within 16-tile
  const int lk = (l >> 4) * 8;    // k offset within 32-step
  f32x4 acc[2][4] = {};
#pragma unroll
  for (int ks = 0; ks < K / 32; ++ks) {
    f16x8 af[2], bf[4];
#pragma unroll
    for (int m = 0; m < 2; ++m) {
      int r = wv * 32 + m * 16 + lr;
      unsigned int off = (unsigned int)((r * K + ks * 32 + lk) * 2) ^ ((r & 7) << 4);
      af[m] = *reinterpret_cast<const f16x8*>(sA + off);
    }
#pragma unroll
    for (int n = 0; n < 4; ++n) {
      int cc = n * 16 + lr;
      unsigned int off = (unsigned int)((cc * K + ks * 32 + lk) * 2) ^ ((cc & 7) << 4);
      bf[n] = *reinterpret_cast<const f16x8*>(sB + off);
    }
#pragma unroll
    for (int m = 0; m < 2; ++m)
#pragma unroll
      for (int n = 0; n < 4; ++n)
        acc[m][n] = __builtin_amdgcn_mfma_f32_16x16x32_f16(af[m], bf[n], acc[m][n],
                                                           0, 0, 0);
  }
  // epilogue: C frag row=(l>>4)*4+j, col=lr; scale by dinv, store fp16
#pragma unroll
  for (int m = 0; m < 2; ++m) {
#pragma unroll
    for (int j = 0; j < 4; ++j) {
      int row = brow + wv * 32 + m * 16 + (l >> 4) * 4 + j;
      if (row < N) {
        float di = dinv[row];
#pragma unroll
        for (int n = 0; n < 4; ++n) {
          float v = acc[m][n][j] * di;
          H[(size_t)row * 64 + n * 16 + lr] = __float2half_rn(v);
        }
      }
    }
  }
}

// One wave per node: out[i] = act(dinv[i]*(sum_edges hs[esrc] + hs[i]) + b)
template <bool RELU, bool OUT_HALF>
__global__ __launch_bounds__(256) void agg_kernel(const __half* __restrict__ hs,
                                                  const int* __restrict__ rowptr,
                                                  const int* __restrict__ esrc,
                                                  const float* __restrict__ dinv,
                                                  const float* __restrict__ b,
                                                  void* __restrict__ outv, int N) {
  const int node = blockIdx.x * 4 + (threadIdx.x >> 6);
  if (node >= N) return;
  const int lane = threadIdx.x & 63;
  const int g = lane >> 4, cl = lane & 15;
  const uint2* hv = reinterpret_cast<const uint2*>(hs);
  const int beg = rowptr[node], end = rowptr[node + 1];
  float4 a0 = make_float4(0.f, 0.f, 0.f, 0.f);
  float4 a1 = make_float4(0.f, 0.f, 0.f, 0.f);
  int k = beg + g;
  for (; k + 4 < end; k += 8) {
    int s0 = esrc[k], s1 = esrc[k + 4];
    uint2 v0 = hv[(size_t)s0 * 16 + cl];
    uint2 v1 = hv[(size_t)s1 * 16 + cl];
    float2 f00 = __half22float2(*reinterpret_cast<__half2*>(&v0.x));
    float2 f01 = __half22float2(*reinterpret_cast<__half2*>(&v0.y));
    float2 f10 = __half22float2(*reinterpret_cast<__half2*>(&v1.x));
    float2 f11 = __half22float2(*reinterpret_cast<__half2*>(&v1.y));
    a0.x += f00.x; a0.y += f00.y; a0.z += f01.x; a0.w += f01.y;
    a1.x += f10.x; a1.y += f10.y; a1.z += f11.x; a1.w += f11.y;
  }
  if (k < end) {
    uint2 v0 = hv[(size_t)esrc[k] * 16 + cl];
    float2 f00 = __half22float2(*reinterpret_cast<__half2*>(&v0.x));
    float2 f01 = __half22float2(*reinterpret_cast<__half2*>(&v0.y));
    a0.x += f00.x; a0.y += f00.y; a0.z += f01.x; a0.w += f01.y;
  }
  a0.x += a1.x; a0.y += a1.y; a0.z += a1.z; a0.w += a1.w;
#pragma unroll
  for (int off = 16; off <= 32; off <<= 1) {
    a0.x += __shfl_xor(a0.x, off);
    a0.y += __shfl_xor(a0.y, off);
    a0.z += __shfl_xor(a0.z, off);
    a0.w += __shfl_xor(a0.w, off);
  }
  if (g == 0) {
    uint2 sv = hv[(size_t)node * 16 + cl];
    float2 s01 = __half22float2(*reinterpret_cast<__half2*>(&sv.x));
    float2 s23 = __half22float2(*reinterpret_cast<__half2*>(&sv.y));
    float di = dinv[node];
    float4 bb = reinterpret_cast<const float4*>(b)[cl];
    float4 r;
    r.x = (a0.x + s01.x) * di + bb.x;
    r.y = (a0.y + s01.y) * di + bb.y;
    r.z = (a0.z + s23.x) * di + bb.z;
    r.w = (a0.w + s23.y) * di + bb.w;
    if (RELU) {
      r.x = fmaxf(r.x, 0.f); r.y = fmaxf(r.y, 0.f);
      r.z = fmaxf(r.z, 0.f); r.w = fmaxf(r.w, 0.f);
    }
    if constexpr (OUT_HALF) {
      uint2 pk;
      pk.x = pack2(r.x, r.y);
      pk.y = pack2(r.z, r.w);
      reinterpret_cast<uint2*>(outv)[(size_t)node * 16 + cl] = pk;
    } else {
      reinterpret_cast<float4*>(outv)[(size_t)node * 16 + cl] = r;
    }
  }
}

extern "C" void kernel_launch(void* const* d_in, const int* in_sizes, int n_in,
                              void* d_out, int out_size, void* d_ws, size_t ws_size,
                              hipStream_t stream) {
  const float* x  = (const float*)d_in[0];
  const int*   ei = (const int*)d_in[1];
  const float* W1 = (const float*)d_in[2];
  const float* b1 = (const float*)d_in[3];
  const float* W2 = (const float*)d_in[4];
  const float* b2 = (const float*)d_in[5];
  const int N = in_sizes[0] / 128;
  const int E = in_sizes[1] / 2;
  const int* src = ei;
  const int* dst = ei + E;
  const int nb = (N + 127) >> 7;  // 782 buckets

  char* ws = (char*)d_ws;
  int*    bcursor = (int*)ws;                       // nb ints
  int*    bbase   = (int*)(ws + (1 << 19));         // nb ints   @ 512KB
  float*  dinv    = (float*)(ws + (1 << 20));       // N floats  @ 1MB
  int*    rowptr  = (int*)(ws + 3 * (1 << 19));     // N+1 ints  @ 1.5MB
  int*    esrc    = (int*)(ws + (1 << 21));         // E ints    @ 2MB   (6.4MB)
  int*    ebuck   = (int*)(ws + 9 * (1 << 20));     // nb*BCAP   @ 9MB   (12.8MB)
  __half* hs      = (__half*)(ws + 22 * (1 << 20)); // N*64 fp16 @ 22MB  (12.8MB)
  __half* y1h     = (__half*)(ws + 36 * (1 << 20)); // N*64 fp16 @ 36MB  (12.8MB)
  float*  out = (float*)d_out;

  // CSR build (shared by both layers)
  initcur_kernel<<<(nb + 255) / 256, 256, 0, stream>>>(bcursor, nb);
  chunksort_kernel<<<(E + CHUNK - 1) / CHUNK, 256, 0, stream>>>(src, dst, bcursor,
                                                                ebuck, E, nb);
  bscan_kernel<<<1, 1024, 0, stream>>>(bcursor, bbase, nb);
  bucketsort_kernel<<<nb, 256, 0, stream>>>(ebuck, bcursor, bbase, esrc, rowptr,
                                            dinv, N, E, nb);

  const int gemmGrid = (N + 127) / 128;
  const int aggGrid = (N + 3) / 4;
  // layer 1: hs1(fp16) -> hs ; y1(fp16, relu) -> y1h
  gemm_mfma<128, false><<<gemmGrid, 256, 0, stream>>>(x, W1, dinv, hs, N);
  agg_kernel<true, true><<<aggGrid, 256, 0, stream>>>(hs, rowptr, esrc, dinv, b1,
                                                      y1h, N);
  // layer 2: hs2(fp16) -> hs (reuse) ; y2(fp32) -> out
  gemm_mfma<64, true><<<gemmGrid, 256, 0, stream>>>(y1h, W2, dinv, hs, N);
  agg_kernel<false, false><<<aggGrid, 256, 0, stream>>>(hs, rowptr, esrc, dinv, b2,
                                                        out, N);
}